// Round 1
// baseline (188.663 us; speedup 1.0000x reference)
//
#include <hip/hip_runtime.h>
#include <math.h>

#if __has_builtin(__builtin_amdgcn_exp2f)
#define EXP2F(x) __builtin_amdgcn_exp2f(x)
#else
#define EXP2F(x) exp2f(x)
#endif
#if __has_builtin(__builtin_amdgcn_sqrtf)
#define SQRTF(x) __builtin_amdgcn_sqrtf(x)
#else
#define SQRTF(x) sqrtf(x)
#endif

#define NPTS 8192
#define TI 256              // i-rows per block (== threads)
#define NJ 512              // j per LDS chunk
#define IB (NPTS / TI)      // 32
#define JCH (NPTS / NJ)     // 16
#define BLKS_PER_MAT (IB * JCH)  // 512
#define NPART 11            // partial-sum rows (3 aa + 3 bb + 3 ab + sd + sq)

// acc (double) layout:
//  [0..7]  prep sums: Sb, Qb, Mxb, Myb, St, Qt, Mxt, Myt
//  [8 + r*BLKS_PER_MAT + blk] : per-block partials, r in [0, NPART)

__device__ inline double wred(double v) {
#pragma unroll
  for (int o = 32; o > 0; o >>= 1) v += __shfl_down(v, o, 64);
  return v;
}

// block reduction (256 threads); returns full sum to all threads
__device__ inline double bred(double v, double* sm) {
  v = wred(v);
  int w = threadIdx.x >> 6;
  __syncthreads();
  if ((threadIdx.x & 63) == 0) sm[w] = v;
  __syncthreads();
  return sm[0] + sm[1] + sm[2] + sm[3];
}

__global__ __launch_bounds__(256) void prep_kernel(
    const float* __restrict__ base, const float* __restrict__ target,
    const float* __restrict__ log_scale, const float* __restrict__ w1,
    const float* __restrict__ b1, const float* __restrict__ w2,
    const float* __restrict__ b2, float* __restrict__ xs,
    float* __restrict__ ys, float* __restrict__ us, double* __restrict__ acc,
    int n) {
  int gid = blockIdx.x * 256 + threadIdx.x;
  int isT = gid >= n;  // block-uniform (n % 256 == 0)
  int idx = isT ? gid - n : gid;
  const float* pts = isT ? target : base;
  float sx = __expf(log_scale[0]);
  float sy = __expf(log_scale[1]);
  float x = pts[2 * idx] * sx;
  float y = pts[2 * idx + 1] * sy;
  // weight net: relu(p @ w1 + b1) @ w2 + b2 ; u = softplus(logit) + 1e-6
  float logit = b2[0];
#pragma unroll
  for (int k = 0; k < 32; ++k) {
    float h = fmaf(x, w1[k], fmaf(y, w1[32 + k], b1[k]));
    h = fmaxf(h, 0.f);
    logit = fmaf(h, w2[k], logit);
  }
  float u = fmaxf(logit, 0.f) + log1pf(__expf(-fabsf(logit))) + 1e-6f;
  xs[gid] = x;
  ys[gid] = y;
  us[gid] = u;
  double su = wred((double)u);
  double sq = wred((double)u * (double)u);
  double swx = wred((double)u * (double)x);
  double swy = wred((double)u * (double)y);
  if ((threadIdx.x & 63) == 0) {
    double* a = acc + (isT ? 4 : 0);
    atomicAdd(a + 0, su);
    atomicAdd(a + 1, sq);
    atomicAdd(a + 2, swx);
    atomicAdd(a + 3, swy);
  }
}

__global__ __launch_bounds__(256) void pair_kernel(
    const float* __restrict__ xs, const float* __restrict__ ys,
    const float* __restrict__ us, const float* __restrict__ log_sigmas,
    double* __restrict__ acc, int n) {
  __shared__ __align__(16) float sxj[NJ];
  __shared__ __align__(16) float syj[NJ];
  __shared__ __align__(16) float suj[NJ];
  __shared__ double sred[4];

  int b = blockIdx.x;
  int m = b / BLKS_PER_MAT;           // 0: AA, 1: BB, 2: AB
  int rem = b - m * BLKS_PER_MAT;     // block index within matrix
  int ib = rem / JCH;
  int jc = rem - ib * JCH;

  float s0 = __expf(log_sigmas[0]);
  float s1 = __expf(log_sigmas[1]);
  float s2 = __expf(log_sigmas[2]);
  const float L2E = 1.4426950408889634f;
  float na0 = -L2E / (2.f * s0 * s0);
  float na1 = -L2E / (2.f * s1 * s1);
  float na2 = -L2E / (2.f * s2 * s2);
  // sigma ratio fast path: inv0 == 16*inv2, inv1 == 4*inv2
  bool fast = (fabsf(na0 - 16.f * na2) <= 1e-3f * fabsf(na0)) &&
              (fabsf(na1 - 4.f * na2) <= 1e-3f * fabsf(na1));

  const float *xi_a, *yi_a, *ui_a, *xj_a, *yj_a, *uj_a;
  float cx = 0.f, cy = 0.f;
  if (m == 0) {
    xi_a = xs; yi_a = ys; ui_a = us;
    xj_a = xs; yj_a = ys; uj_a = us;
  } else if (m == 1) {
    xi_a = xs + n; yi_a = ys + n; ui_a = us + n;
    xj_a = xs + n; yj_a = ys + n; uj_a = us + n;
  } else {
    xi_a = xs; yi_a = ys; ui_a = us;
    xj_a = xs + n; yj_a = ys + n; uj_a = us + n;
    double Sb = acc[0], St = acc[4];
    cx = (float)(acc[2] / Sb - acc[6] / St);
    cy = (float)(acc[3] / Sb - acc[7] / St);
  }

  int j0 = jc * NJ;
  for (int t = threadIdx.x; t < NJ; t += 256) {
    sxj[t] = xj_a[j0 + t];
    syj[t] = yj_a[j0 + t];
    suj[t] = uj_a[j0 + t];
  }
  __syncthreads();

  int i = ib * TI + threadIdx.x;
  float xi = xi_a[i], yi = yi_a[i], ui = ui_a[i];
  float xic = xi - cx, yic = yi - cy;  // centered-offset i point (AB only)

  float a0 = 0.f, a1 = 0.f, a2 = 0.f;  // sum_j u_j * k_sigma
  float sd = 0.f, sq = 0.f;            // AB only: sum dist, sum dist^2

  if (m < 2) {
    if (fast) {
#pragma unroll 2
      for (int j = 0; j < NJ; j += 4) {
        float4 x4 = *(const float4*)&sxj[j];
        float4 y4 = *(const float4*)&syj[j];
        float4 u4 = *(const float4*)&suj[j];
        float xv[4] = {x4.x, x4.y, x4.z, x4.w};
        float yv[4] = {y4.x, y4.y, y4.z, y4.w};
        float uv[4] = {u4.x, u4.y, u4.z, u4.w};
#pragma unroll
        for (int q = 0; q < 4; ++q) {
          float dx = xi - xv[q], dy = yi - yv[q];
          float d2 = fmaf(dy, dy, dx * dx);
          float k2 = EXP2F(d2 * na2);
          float t2 = k2 * k2;
          float k1 = t2 * t2;    // k2^4
          float t1 = k1 * k1;
          float k0 = t1 * t1;    // k2^16
          a0 = fmaf(uv[q], k0, a0);
          a1 = fmaf(uv[q], k1, a1);
          a2 = fmaf(uv[q], k2, a2);
        }
      }
    } else {
#pragma unroll 2
      for (int j = 0; j < NJ; j += 4) {
        float4 x4 = *(const float4*)&sxj[j];
        float4 y4 = *(const float4*)&syj[j];
        float4 u4 = *(const float4*)&suj[j];
        float xv[4] = {x4.x, x4.y, x4.z, x4.w};
        float yv[4] = {y4.x, y4.y, y4.z, y4.w};
        float uv[4] = {u4.x, u4.y, u4.z, u4.w};
#pragma unroll
        for (int q = 0; q < 4; ++q) {
          float dx = xi - xv[q], dy = yi - yv[q];
          float d2 = fmaf(dy, dy, dx * dx);
          float k0 = EXP2F(d2 * na0);
          float k1 = EXP2F(d2 * na1);
          float k2 = EXP2F(d2 * na2);
          a0 = fmaf(uv[q], k0, a0);
          a1 = fmaf(uv[q], k1, a1);
          a2 = fmaf(uv[q], k2, a2);
        }
      }
    }
  } else {
    if (fast) {
#pragma unroll 2
      for (int j = 0; j < NJ; j += 4) {
        float4 x4 = *(const float4*)&sxj[j];
        float4 y4 = *(const float4*)&syj[j];
        float4 u4 = *(const float4*)&suj[j];
        float xv[4] = {x4.x, x4.y, x4.z, x4.w};
        float yv[4] = {y4.x, y4.y, y4.z, y4.w};
        float uv[4] = {u4.x, u4.y, u4.z, u4.w};
#pragma unroll
        for (int q = 0; q < 4; ++q) {
          float dxc = xic - xv[q], dyc = yic - yv[q];
          float d2c = fmaf(dyc, dyc, dxc * dxc);
          float dxu = xi - xv[q], dyu = yi - yv[q];
          float d2u = fmaf(dyu, dyu, dxu * dxu);
          float k2 = EXP2F(d2c * na2);
          float t2 = k2 * k2;
          float k1 = t2 * t2;
          float t1 = k1 * k1;
          float k0 = t1 * t1;
          a0 = fmaf(uv[q], k0, a0);
          a1 = fmaf(uv[q], k1, a1);
          a2 = fmaf(uv[q], k2, a2);
          sd += SQRTF(d2u);
          sq += d2u;
        }
      }
    } else {
#pragma unroll 2
      for (int j = 0; j < NJ; j += 4) {
        float4 x4 = *(const float4*)&sxj[j];
        float4 y4 = *(const float4*)&syj[j];
        float4 u4 = *(const float4*)&suj[j];
        float xv[4] = {x4.x, x4.y, x4.z, x4.w};
        float yv[4] = {y4.x, y4.y, y4.z, y4.w};
        float uv[4] = {u4.x, u4.y, u4.z, u4.w};
#pragma unroll
        for (int q = 0; q < 4; ++q) {
          float dxc = xic - xv[q], dyc = yic - yv[q];
          float d2c = fmaf(dyc, dyc, dxc * dxc);
          float dxu = xi - xv[q], dyu = yi - yv[q];
          float d2u = fmaf(dyu, dyu, dxu * dxu);
          float k0 = EXP2F(d2c * na0);
          float k1 = EXP2F(d2c * na1);
          float k2 = EXP2F(d2c * na2);
          a0 = fmaf(uv[q], k0, a0);
          a1 = fmaf(uv[q], k1, a1);
          a2 = fmaf(uv[q], k2, a2);
          sd += SQRTF(d2u);
          sq += d2u;
        }
      }
    }
  }

  // per-thread contribution to u.K.u is ui * a_s
  double r0 = bred((double)ui * (double)a0, sred);
  double r1 = bred((double)ui * (double)a1, sred);
  double r2 = bred((double)ui * (double)a2, sred);
  int base_r = (m == 0) ? 0 : (m == 1 ? 3 : 6);
  int blk = rem;
  if (threadIdx.x == 0) {
    acc[8 + (base_r + 0) * BLKS_PER_MAT + blk] = r0;
    acc[8 + (base_r + 1) * BLKS_PER_MAT + blk] = r1;
    acc[8 + (base_r + 2) * BLKS_PER_MAT + blk] = r2;
  }
  if (m == 2) {
    double r3 = bred((double)sd, sred);
    double r4 = bred((double)sq, sred);
    if (threadIdx.x == 0) {
      acc[8 + 9 * BLKS_PER_MAT + blk] = r3;
      acc[8 + 10 * BLKS_PER_MAT + blk] = r4;
    }
  }
}

__global__ __launch_bounds__(256) void final_kernel(
    const double* __restrict__ acc, const float* __restrict__ g_w1,
    const float* __restrict__ g_b1, const float* __restrict__ g_w2,
    const float* __restrict__ g_b2, const float* __restrict__ bias,
    float* __restrict__ out, int n) {
  __shared__ double sred[4];
  __shared__ double sums[NPART];
  for (int r = 0; r < NPART; ++r) {
    const double* p = acc + 8 + r * BLKS_PER_MAT;
    double v = p[threadIdx.x] + p[threadIdx.x + 256];
    v = bred(v, sred);
    if (threadIdx.x == 0) sums[r] = v;
  }
  __syncthreads();
  if (threadIdx.x == 0) {
    double Sb = acc[0], Qb = acc[1];
    double St = acc[4], Qt = acc[5];
    double pb[3];
    for (int s = 0; s < 3; ++s)
      pb[s] = sums[s] / (Sb * Sb) + sums[3 + s] / (St * St) -
              2.0 * sums[6 + s] / (Sb * St);
    double NN = (double)n;
    double NM = NN * NN;
    double mean_d = sums[9] / NM;
    double var_d = (sums[10] - sums[9] * sums[9] / NM) / (NM - 1.0);
    double wv = (Qb / (Sb * Sb) - 1.0 / NN) / (NN - 1.0) +
                (Qt / (St * St) - 1.0 / NN) / (NN - 1.0);
    float st[4] = {(float)mean_d, (float)var_d, 0.f, (float)wv};
    float gl[3] = {g_b2[0], g_b2[1], g_b2[2]};
    for (int k = 0; k < 32; ++k) {
      float h = g_b1[k];
      for (int t = 0; t < 4; ++t) h = fmaf(st[t], g_w1[t * 32 + k], h);
      h = fmaxf(h, 0.f);
      for (int s = 0; s < 3; ++s) gl[s] = fmaf(h, g_w2[k * 3 + s], gl[s]);
    }
    float gw[3];
    float gsum = 0.f;
    for (int s = 0; s < 3; ++s) {
      gw[s] = fmaxf(gl[s], 0.f) + log1pf(__expf(-fabsf(gl[s])));
      gsum += gw[s];
    }
    double r = 0.0;
    for (int s = 0; s < 3; ++s) r += (double)(gw[s] / gsum) * pb[s];
    out[0] = (float)(r + (double)bias[0]);
  }
}

extern "C" void kernel_launch(void* const* d_in, const int* in_sizes, int n_in,
                              void* d_out, int out_size, void* d_ws,
                              size_t ws_size, hipStream_t stream) {
  const float* base = (const float*)d_in[0];
  const float* target = (const float*)d_in[1];
  const float* log_sigmas = (const float*)d_in[2];
  const float* log_scale = (const float*)d_in[3];
  const float* wn_w1 = (const float*)d_in[4];
  const float* wn_b1 = (const float*)d_in[5];
  const float* wn_w2 = (const float*)d_in[6];
  const float* wn_b2 = (const float*)d_in[7];
  const float* g_w1 = (const float*)d_in[8];
  const float* g_b1 = (const float*)d_in[9];
  const float* g_w2 = (const float*)d_in[10];
  const float* g_b2 = (const float*)d_in[11];
  const float* bias = (const float*)d_in[12];
  int n = in_sizes[0] / 2;  // 8192

  float* xs = (float*)d_ws;       // [2n] scaled x (base then target)
  float* ys = xs + 2 * n;         // [2n]
  float* us = ys + 2 * n;         // [2n] unnormalized weights
  double* acc = (double*)((char*)d_ws + (size_t)6 * n * sizeof(float));

  hipMemsetAsync(acc, 0, 8 * sizeof(double), stream);
  prep_kernel<<<(2 * n) / 256, 256, 0, stream>>>(
      base, target, log_scale, wn_w1, wn_b1, wn_w2, wn_b2, xs, ys, us, acc, n);
  pair_kernel<<<3 * BLKS_PER_MAT, 256, 0, stream>>>(xs, ys, us, log_sigmas,
                                                    acc, n);
  final_kernel<<<1, 256, 0, stream>>>(acc, g_w1, g_b1, g_w2, g_b2, bias,
                                      (float*)d_out, n);
}

// Round 2
// 165.932 us; speedup vs baseline: 1.1370x; 1.1370x over previous
//
#include <hip/hip_runtime.h>
#include <math.h>

#if __has_builtin(__builtin_amdgcn_exp2f)
#define EXP2F(x) __builtin_amdgcn_exp2f(x)
#else
#define EXP2F(x) exp2f(x)
#endif
#if __has_builtin(__builtin_amdgcn_sqrtf)
#define SQRTF(x) __builtin_amdgcn_sqrtf(x)
#else
#define SQRTF(x) sqrtf(x)
#endif

#define NPTS 8192
#define NJ 512          // j per tile (LDS staged)
#define TI 512          // i per tile (2 per thread, 256 threads)
#define T16 16          // tiles per dimension (8192/512)
#define NTRI 136        // upper-tri tile count = 16*17/2
#define NBLK (256 + 2 * NTRI)  // 528: AB first (heavier), then AA, BB
#define L2E 1.4426950408889634f

__device__ inline double wred_d(double v) {
#pragma unroll
  for (int o = 32; o > 0; o >>= 1) v += __shfl_down(v, o, 64);
  return v;
}

// block reduction over 256 threads; result broadcast to all threads
__device__ inline double bred(double v, double* sm) {
  v = wred_d(v);
  __syncthreads();
  if ((threadIdx.x & 63) == 0) sm[threadIdx.x >> 6] = v;
  __syncthreads();
  return sm[0] + sm[1] + sm[2] + sm[3];
}

// wave 0 reduces the 64 prep slots into smean[8] = {Sb,Qb,Mxb,Myb,St,Qt,Mxt,Myt}
__device__ inline void slot_reduce(const double* slot, double* smean) {
  if (threadIdx.x < 64) {
    int l = threadIdx.x;
    const double* sl = slot + l * 4;
#pragma unroll
    for (int c = 0; c < 4; ++c) {
      double v = sl[c];
      double vb = (l < 32) ? v : 0.0;
      double vt = (l < 32) ? 0.0 : v;
      vb = wred_d(vb);
      vt = wred_d(vt);
      if (l == 0) {
        smean[c] = vb;
        smean[4 + c] = vt;
      }
    }
  }
}

__global__ __launch_bounds__(256) void prep_kernel(
    const float* __restrict__ base, const float* __restrict__ target,
    const float* __restrict__ log_sigmas, const float* __restrict__ log_scale,
    const float* __restrict__ w1, const float* __restrict__ b1,
    const float* __restrict__ w2, const float* __restrict__ b2,
    float2* __restrict__ pxy, float* __restrict__ pu,
    double* __restrict__ slot, unsigned* __restrict__ ctr, int n) {
  __shared__ double sm[4];
  int gid = blockIdx.x * 256 + threadIdx.x;
  int isT = gid >= n;  // uniform per block (n % 256 == 0)
  const float* pts = isT ? target : base;
  int idx = isT ? gid - n : gid;
  float ex = __expf(log_scale[0]);
  float ey = __expf(log_scale[1]);
  float s2 = __expf(log_sigmas[2]);
  float r2 = __fsqrt_rn(L2E / (2.f * s2 * s2));  // coord pre-scale for band 2
  float2 p = ((const float2*)pts)[idx];
  float xr = p.x * ex, yr = p.y * ey;  // MLP input space (no r2!)
  float logit = b2[0];
#pragma unroll
  for (int k = 0; k < 32; ++k) {
    float h = fmaf(xr, w1[k], fmaf(yr, w1[32 + k], b1[k]));
    h = fmaxf(h, 0.f);
    logit = fmaf(h, w2[k], logit);
  }
  float u = fmaxf(logit, 0.f) + log1pf(__expf(-fabsf(logit))) + 1e-6f;
  float X = xr * r2, Y = yr * r2;
  pxy[gid] = make_float2(X, Y);
  pu[gid] = u;
  double su = bred((double)u, sm);
  double qu = bred((double)u * (double)u, sm);
  double mx = bred((double)u * (double)X, sm);
  double my = bred((double)u * (double)Y, sm);
  if (threadIdx.x == 0) {
    double* s = slot + blockIdx.x * 4;
    s[0] = su;
    s[1] = qu;
    s[2] = mx;
    s[3] = my;
    if (blockIdx.x == 0) *ctr = 0u;
  }
}

template <bool AB, bool FAST>
__device__ inline void tile_loop(const float4* sxy4, const float2* su2,
                                 const float2* sb2, float x0, float y0,
                                 float x1, float y1, float al0, float al1,
                                 float rr0, float rr1, float acc[2][3],
                                 float& sdo, float& sqo) {
  float sd = 0.f, sq = 0.f;
#pragma unroll 2
  for (int jj = 0; jj < NJ / 2; ++jj) {
    float4 xy = sxy4[jj];   // {x0,y0,x1,y1} for two j points (broadcast)
    float2 u2 = su2[jj];
    float bj[2];
    if constexpr (AB) {
      float2 b2v = sb2[jj];
      bj[0] = b2v.x;
      bj[1] = b2v.y;
    }
    float xj[2] = {xy.x, xy.z};
    float yj[2] = {xy.y, xy.w};
    float uj[2] = {u2.x, u2.y};
#pragma unroll
    for (int q = 0; q < 2; ++q) {
#pragma unroll
      for (int i = 0; i < 2; ++i) {
        float dx = (i ? x1 : x0) - xj[q];
        float dy = (i ? y1 : y0) - yj[q];
        float s = fmaf(dy, dy, dx * dx);  // = d2_centered * (ln2e/2s2^2)
        float k2 = EXP2F(-s);
        float k0, k1;
        if constexpr (FAST) {
          float t = k2 * k2;
          k1 = t * t;        // k2^4  (sigma ratio 1:2)
          float t1 = k1 * k1;
          k0 = t1 * t1;      // k2^16 (sigma ratio 1:4)
        } else {
          k1 = EXP2F(-s * rr1);
          k0 = EXP2F(-s * rr0);
        }
        acc[i][0] = fmaf(uj[q], k0, acc[i][0]);
        acc[i][1] = fmaf(uj[q], k1, acc[i][1]);
        acc[i][2] = fmaf(uj[q], k2, acc[i][2]);
        if constexpr (AB) {
          // uncentered scaled d2 = s + alpha_i - beta_j (clamp vs cancellation)
          float d2u = fmaxf((s + (i ? al1 : al0)) - bj[q], 0.f);
          sd += SQRTF(d2u);
          sq += d2u;
        }
      }
    }
  }
  sdo = sd;
  sqo = sq;
}

__global__ __launch_bounds__(256) void pair_kernel(
    const float2* __restrict__ pxy, const float* __restrict__ pu,
    const double* __restrict__ slot, double* __restrict__ paa,
    double* __restrict__ pbb, double* __restrict__ pab,
    double* __restrict__ psd, double* __restrict__ psq,
    unsigned* __restrict__ ctr, const float* __restrict__ log_sigmas,
    const float* __restrict__ g_w1, const float* __restrict__ g_b1,
    const float* __restrict__ g_w2, const float* __restrict__ g_b2,
    const float* __restrict__ bias, float* __restrict__ out, int n) {
  __shared__ __align__(16) float2 sxy[NJ];
  __shared__ float su[NJ];
  __shared__ float sb[NJ];
  __shared__ double sm[4];
  __shared__ double smean[8];
  __shared__ int lastf;

  int b = blockIdx.x, m, it, jt, pidx;
  if (b < 256) {  // AB: full 16x16 grid
    m = 2;
    pidx = b;
    it = b >> 4;
    jt = b & 15;
  } else {  // AA / BB: upper-triangle tiles
    int r = b - 256;
    m = (r < NTRI) ? 0 : 1;
    pidx = (m == 0) ? r : r - NTRI;
    int idx = pidx;
    it = 0;
    for (;;) {
      int len = T16 - it;
      if (idx < len) {
        jt = it + idx;
        break;
      }
      idx -= len;
      ++it;
    }
  }
  const float2* pxyI = pxy + ((m == 1) ? n : 0);
  const float* puI = pu + ((m == 1) ? n : 0);
  const float2* pxyJ = pxy + ((m == 0) ? 0 : n);
  const float* puJ = pu + ((m == 0) ? 0 : n);

  int j0 = jt * NJ;
  for (int t = threadIdx.x; t < NJ; t += 256) {
    sxy[t] = pxyJ[j0 + t];
    su[t] = puJ[j0 + t];
  }
  if (m == 2) slot_reduce(slot, smean);  // wave 0 only; needs the barrier below
  __syncthreads();

  float cx = 0.f, cy = 0.f;
  if (m == 2) {
    cx = (float)(smean[2] / smean[0] - smean[6] / smean[4]);
    cy = (float)(smean[3] / smean[0] - smean[7] / smean[4]);
    for (int t = threadIdx.x; t < NJ; t += 256) {
      float2 v = sxy[t];
      sb[t] = 2.f * fmaf(cx, v.x, cy * v.y);  // beta_j
    }
    __syncthreads();
  }

  int i0 = it * TI + threadIdx.x;
  float2 P0 = pxyI[i0], P1 = pxyI[i0 + 256];
  float u0 = puI[i0], u1 = puI[i0 + 256];
  float x0 = P0.x - cx, y0 = P0.y - cy;  // centered for AB; raw for AA/BB
  float x1 = P1.x - cx, y1 = P1.y - cy;
  float al0 = fmaf(2.f * cx, x0, 2.f * cy * y0) + cx * cx + cy * cy;
  float al1 = fmaf(2.f * cx, x1, 2.f * cy * y1) + cx * cx + cy * cy;

  float s0 = __expf(log_sigmas[0]);
  float s1 = __expf(log_sigmas[1]);
  float s2 = __expf(log_sigmas[2]);
  float rr0 = (s2 * s2) / (s0 * s0);
  float rr1 = (s2 * s2) / (s1 * s1);
  bool fast = (fabsf(rr0 - 16.f) <= 0.016f) && (fabsf(rr1 - 4.f) <= 0.004f);

  float acc[2][3] = {};
  float sd = 0.f, sq = 0.f;
  const float4* sxy4 = reinterpret_cast<const float4*>(sxy);
  const float2* su2 = reinterpret_cast<const float2*>(su);
  const float2* sb2 = reinterpret_cast<const float2*>(sb);
  if (m == 2) {
    if (fast)
      tile_loop<true, true>(sxy4, su2, sb2, x0, y0, x1, y1, al0, al1, rr0, rr1,
                            acc, sd, sq);
    else
      tile_loop<true, false>(sxy4, su2, sb2, x0, y0, x1, y1, al0, al1, rr0,
                             rr1, acc, sd, sq);
  } else {
    if (fast)
      tile_loop<false, true>(sxy4, su2, sb2, x0, y0, x1, y1, al0, al1, rr0,
                             rr1, acc, sd, sq);
    else
      tile_loop<false, false>(sxy4, su2, sb2, x0, y0, x1, y1, al0, al1, rr0,
                              rr1, acc, sd, sq);
  }

  double wgt = (m != 2 && it != jt) ? 2.0 : 1.0;  // symmetric off-diag tiles
  double c0 = (double)u0 * (double)acc[0][0] + (double)u1 * (double)acc[1][0];
  double c1 = (double)u0 * (double)acc[0][1] + (double)u1 * (double)acc[1][1];
  double c2 = (double)u0 * (double)acc[0][2] + (double)u1 * (double)acc[1][2];
  double r0 = bred(c0, sm) * wgt;
  double r1 = bred(c1, sm) * wgt;
  double r2d = bred(c2, sm) * wgt;
  double* prow = (m == 0) ? paa : (m == 1) ? pbb : pab;
  int stride = (m == 2) ? 256 : NTRI;
  if (threadIdx.x == 0) {
    prow[0 * stride + pidx] = r0;
    prow[1 * stride + pidx] = r1;
    prow[2 * stride + pidx] = r2d;
  }
  if (m == 2) {
    double rsd = bred((double)sd, sm);
    double rsq = bred((double)sq, sm);
    if (threadIdx.x == 0) {
      psd[pidx] = rsd;
      psq[pidx] = rsq;
    }
  }

  // ---- last-block final reduction (release/acquire via device fence) ----
  if (threadIdx.x == 0) {
    __threadfence();
    unsigned old = atomicAdd(ctr, 1u);
    lastf = (old == NBLK - 1) ? 1 : 0;
  }
  __syncthreads();
  if (lastf == 0) return;
  __threadfence();

  slot_reduce(slot, smean);
  __syncthreads();
  int t = threadIdx.x;
  double vaa[3], vbb[3], vab[3];
  for (int s = 0; s < 3; ++s) {
    vaa[s] = bred((t < NTRI) ? paa[s * NTRI + t] : 0.0, sm);
    vbb[s] = bred((t < NTRI) ? pbb[s * NTRI + t] : 0.0, sm);
    vab[s] = bred(pab[s * 256 + t], sm);
  }
  double sdt = bred(psd[t], sm);
  double sqt = bred(psq[t], sm);

  if (threadIdx.x == 0) {
    double Sb = smean[0], Qb = smean[1], St = smean[4], Qt = smean[5];
    double pband[3];
    for (int s = 0; s < 3; ++s)
      pband[s] = vaa[s] / (Sb * Sb) + vbb[s] / (St * St) -
                 2.0 * vab[s] / (Sb * St);
    double s2d = (double)s2;
    double r2sq = (double)L2E / (2.0 * s2d * s2d);
    double sd_real = sdt / sqrt(r2sq);
    double sq_real = sqt / r2sq;
    double NN = (double)n;
    double NM = NN * NN;
    double mean_d = sd_real / NM;
    double var_d = (sq_real - sd_real * sd_real / NM) / (NM - 1.0);
    double wv = (Qb / (Sb * Sb) - 1.0 / NN) / (NN - 1.0) +
                (Qt / (St * St) - 1.0 / NN) / (NN - 1.0);
    float st[4] = {(float)mean_d, (float)var_d, 0.f, (float)wv};
    float gl[3] = {g_b2[0], g_b2[1], g_b2[2]};
    for (int k = 0; k < 32; ++k) {
      float h = g_b1[k];
      for (int c = 0; c < 4; ++c) h = fmaf(st[c], g_w1[c * 32 + k], h);
      h = fmaxf(h, 0.f);
      for (int s = 0; s < 3; ++s) gl[s] = fmaf(h, g_w2[k * 3 + s], gl[s]);
    }
    float gw[3];
    float gsum = 0.f;
    for (int s = 0; s < 3; ++s) {
      gw[s] = fmaxf(gl[s], 0.f) + log1pf(__expf(-fabsf(gl[s])));
      gsum += gw[s];
    }
    double r = 0.0;
    for (int s = 0; s < 3; ++s) r += (double)(gw[s] / gsum) * pband[s];
    out[0] = (float)(r + (double)bias[0]);
  }
}

extern "C" void kernel_launch(void* const* d_in, const int* in_sizes, int n_in,
                              void* d_out, int out_size, void* d_ws,
                              size_t ws_size, hipStream_t stream) {
  const float* base = (const float*)d_in[0];
  const float* target = (const float*)d_in[1];
  const float* log_sigmas = (const float*)d_in[2];
  const float* log_scale = (const float*)d_in[3];
  const float* wn_w1 = (const float*)d_in[4];
  const float* wn_b1 = (const float*)d_in[5];
  const float* wn_w2 = (const float*)d_in[6];
  const float* wn_b2 = (const float*)d_in[7];
  const float* g_w1 = (const float*)d_in[8];
  const float* g_b1 = (const float*)d_in[9];
  const float* g_w2 = (const float*)d_in[10];
  const float* g_b2 = (const float*)d_in[11];
  const float* bias = (const float*)d_in[12];
  int n = in_sizes[0] / 2;  // 8192

  double* dbase = (double*)d_ws;
  double* slot = dbase;             // 64 * 4
  double* paa = dbase + 256;        // 3 * 136
  double* pbb = paa + 3 * NTRI;     // 3 * 136
  double* pab = pbb + 3 * NTRI;     // 3 * 256
  double* psd = pab + 3 * 256;      // 256
  double* psq = psd + 256;          // 256
  double* dend = psq + 256;
  float2* pxy = (float2*)dend;      // 2n
  float* pu = (float*)(pxy + 2 * n);  // 2n
  unsigned* ctr = (unsigned*)(pu + 2 * n);

  prep_kernel<<<(2 * n) / 256, 256, 0, stream>>>(
      base, target, log_sigmas, log_scale, wn_w1, wn_b1, wn_w2, wn_b2, pxy, pu,
      slot, ctr, n);
  pair_kernel<<<NBLK, 256, 0, stream>>>(pxy, pu, slot, paa, pbb, pab, psd, psq,
                                        ctr, log_sigmas, g_w1, g_b1, g_w2,
                                        g_b2, bias, (float*)d_out, n);
}